// Round 12
// baseline (374.302 us; speedup 1.0000x reference)
//
#include <hip/hip_runtime.h>
#include <hip/hip_bf16.h>
#include <hip/hip_fp16.h>

#define N_TOK 524288
#define DM 256
#define HID 512
#define OUTD 32
#define NTYPE 4
#define BM 128                     // rows per tile (32/wave, mt=2)
#define MT 2
#define HC 32
#define NCHUNK (HID / HC)          // 16
#define CHUNK_BYTES (HC * DM * 2)  // 16384
#define NBLK 512                   // partition blocks; N_TOK = NBLK * 1024
#define GRID_X 512                 // persistent blocks: 2/CU x 256 CU

typedef _Float16 half8 __attribute__((ext_vector_type(8)));
typedef float f32x4 __attribute__((ext_vector_type(4)));

#define AS1 __attribute__((address_space(1)))
#define AS3 __attribute__((address_space(3)))

// ---------------- deterministic atomic-free partition ----------------

__global__ void count_kernel(const int* __restrict__ types, int* __restrict__ bc) {
    __shared__ int c[NTYPE];
    int tid = threadIdx.x;
    if (tid < NTYPE) c[tid] = 0;
    __syncthreads();
    int b = blockIdx.x;
    int lane = tid & 63;
    #pragma unroll
    for (int j = 0; j < 4; ++j) {
        int t = types[b * 1024 + j * 256 + tid];
        #pragma unroll
        for (int tt = 0; tt < NTYPE; ++tt) {
            unsigned long long mask = __ballot(t == tt);
            if (lane == 0) atomicAdd(&c[tt], __popcll(mask));
        }
    }
    __syncthreads();
    if (tid < NTYPE) bc[tid * NBLK + b] = c[tid];
}

// meta: [0..3] counts, [4..7] row offsets, [8..11] tile offsets, [12] total tiles
__global__ void scan_blocks_kernel(const int* __restrict__ bc,
                                   int* __restrict__ bb,
                                   int* __restrict__ meta) {
    __shared__ int totals[NTYPE];
    __shared__ int typeoff[NTYPE];
    int wave = threadIdx.x >> 6, lane = threadIdx.x & 63;
    int excl[NBLK / 64];
    int running = 0;
    #pragma unroll
    for (int it = 0; it < NBLK / 64; ++it) {
        int v = bc[wave * NBLK + it * 64 + lane];
        int s = v;
        #pragma unroll
        for (int d = 1; d < 64; d <<= 1) {
            int u = __shfl_up(s, d);
            if (lane >= d) s += u;
        }
        excl[it] = running + s - v;
        running += __shfl(s, 63);
    }
    if (lane == 0) totals[wave] = running;
    __syncthreads();
    if (threadIdx.x == 0) {
        int off = 0, toff = 0;
        for (int tt = 0; tt < NTYPE; ++tt) {
            typeoff[tt] = off;
            meta[tt] = totals[tt];
            meta[4 + tt] = off;
            meta[8 + tt] = toff;
            off += totals[tt];
            toff += (totals[tt] + BM - 1) / BM;
        }
        meta[12] = toff;
    }
    __syncthreads();
    #pragma unroll
    for (int it = 0; it < NBLK / 64; ++it)
        bb[wave * NBLK + it * 64 + lane] = typeoff[wave] + excl[it];
}

__global__ void scatter2_kernel(const int* __restrict__ types,
                                const int* __restrict__ bb,
                                int* __restrict__ idx) {
    __shared__ int base[NTYPE];
    __shared__ int wcnt[4][NTYPE];
    int b = blockIdx.x;
    int tid = threadIdx.x, wave = tid >> 6, lane = tid & 63;
    if (tid < NTYPE) base[tid] = bb[tid * NBLK + b];
    #pragma unroll
    for (int j = 0; j < 4; ++j) {
        __syncthreads();
        int i = b * 1024 + j * 256 + tid;
        int t = types[i];
        int rank = 0;
        #pragma unroll
        for (int tt = 0; tt < NTYPE; ++tt) {
            unsigned long long mask = __ballot(t == tt);
            if (t == tt) rank = __popcll(mask & ((1ull << lane) - 1ull));
            if (lane == 0) wcnt[wave][tt] = __popcll(mask);
        }
        __syncthreads();
        int pre = 0;
        for (int w = 0; w < wave; ++w) pre += wcnt[w][t];
        idx[base[t] + pre + rank] = i;
        __syncthreads();
        if (tid < NTYPE) {
            int tot = 0;
            #pragma unroll
            for (int w = 0; w < 4; ++w) tot += wcnt[w][tid];
            base[tid] += tot;
        }
    }
}

// ---------------- weight prep (unchanged) ----------------

__global__ void wprep_kernel(const float* __restrict__ W1, const float* __restrict__ W2,
                             _Float16* __restrict__ W1T, _Float16* __restrict__ W2T) {
    int i = blockIdx.x * blockDim.x + threadIdx.x;
    if (i < NTYPE * HID * DM) {
        int t = i / (HID * DM);
        int r = i - t * (HID * DM);
        int byteoff = r * 2;
        int hc = byteoff / CHUNK_BYTES;
        int rem = byteoff - hc * CHUNK_BYTES;
        int hr = rem >> 9;
        int brow = rem & 511;
        int d = (brow ^ ((hr & 7) << 4)) >> 1;
        int h = hc * HC + hr;
        W1T[i] = (_Float16)W1[(t * DM + d) * HID + h];
    }
    if (i < NTYPE * OUTD * HID) {
        int t = i / (OUTD * HID);
        int r = i - t * (OUTD * HID);
        int o = r / HID;
        int pg = r - o * HID;
        int hc = pg >> 5;
        int p = pg & 31;
        int lg = p >> 3, j = p & 7;
        int h1 = (j < 4) ? (lg * 4 + j) : (16 + lg * 4 + (j - 4));
        int h = hc * HC + h1;
        W2T[i] = (_Float16)W2[(t * HID + h) * OUTD + o];
    }
}

// ---------------- persistent fused MLP with cross-tile gather pipeline ------
// 512 blocks (2/CU), each ~8 tiles. During tile k's 16 chunks, 2 rows/chunk of
// tile k+1 are gather-DMA'd into wave-private scratch and redistributed into
// afragN one chunk later; chunk 15 prefetches next tile's W1 chunk0 / W2 / b1.
// => HBM gather traffic flows during EVERY chunk instead of in a serial
// prologue (R11's ~50% HBM duty was the bottleneck).

__launch_bounds__(256)
__global__ void fused_mlp_kernel(const float* __restrict__ x,
                                 const int* __restrict__ meta,
                                 const int* __restrict__ idx,
                                 const _Float16* __restrict__ W1T,
                                 const _Float16* __restrict__ W2T,
                                 const float* __restrict__ b1,
                                 const float* __restrict__ b2,
                                 float* __restrict__ out) {
    __shared__ __align__(16) char W1sB[2][CHUNK_BYTES];  // 32 KB W1 double buffer
    __shared__ __align__(16) char scr[4][2][2048];       // 16 KB gather scratch (per wave)
    __shared__ __align__(16) float b1s[2][HID];          // 4 KB bias, tile-parity dbuf
    __shared__ int idsL[4][32];                          // next tile's row ids per wave

    const int ntiles = meta[12];
    int tile = blockIdx.x;
    if (tile >= ntiles) return;

    const int tid = threadIdx.x;
    const int wave = tid >> 6;
    const int lane = tid & 63;
    const int l15 = lane & 15;
    const int lg = lane >> 4;
    char* myScr = &scr[wave][0][0];

    // ---- decode current tile ----
    int tC = (tile >= meta[9]) + (tile >= meta[10]) + (tile >= meta[11]);
    int cntC = meta[tC];
    int rbaseC = (tile - meta[8 + tC]) * BM;
    const int* idxC = idx + meta[4 + tC];
    const char* w1C = (const char*)(W1T + (size_t)tC * HID * DM);
    const _Float16* w2C = W2T + (size_t)tC * OUTD * HID;

    // ---- decode next tile ----
    int tileN = tile + GRID_X;
    bool hasNext = tileN < ntiles;
    int tN = 0, cntN = 1, rbaseN = 0;
    const int* idxN = idx;
    const char* w1N = w1C;
    const _Float16* w2N = w2C;
    const float* b1N = b1;
    if (hasNext) {
        tN = (tileN >= meta[9]) + (tileN >= meta[10]) + (tileN >= meta[11]);
        cntN = meta[tN];
        rbaseN = (tileN - meta[8 + tN]) * BM;
        idxN = idx + meta[4 + tN];
        w1N = (const char*)(W1T + (size_t)tN * HID * DM);
        w2N = W2T + (size_t)tN * OUTD * HID;
        b1N = b1 + tN * HID;
    }

    half8 afragC[MT][8], afragN[MT][8];

// issue gather pair P (rows 2P,2P+1 of the NEXT tile) into scratch half P&1.
// row i source rotated by ((lane-i)&63)*16 so both rows' redistribute reads
// spread banks; LDS dest is wave-uniform base + lane*16 (DMA requirement).
#define GISSUE(P)                                                               \
    {                                                                           \
        int2 rid = *(const int2*)&idsL[wave][2 * (P)];                          \
        const char* s0 = (const char*)(x + (size_t)rid.x * DM) + lane * 16;     \
        const char* s1 = (const char*)(x + (size_t)rid.y * DM)                  \
                         + ((lane - 1) & 63) * 16;                              \
        __builtin_amdgcn_global_load_lds((const AS1 void*)s0,                   \
            (AS3 void*)(myScr + ((P) & 1) * 2048 + lane * 16), 16, 0, 0);       \
        __builtin_amdgcn_global_load_lds((const AS1 void*)s1,                   \
            (AS3 void*)(myScr + ((P) & 1) * 2048 + 1024 + lane * 16), 16, 0, 0);\
    }

// redistribute pair P from scratch half P&1 into DEST regs (8 active lanes:
// l15 in {2P&15, (2P&15)+1}, all lg). Rotation undone via (B + rsel*16)&1023.
#define REDIST(P, DEST)                                                         \
    {                                                                           \
        if ((l15 & 14) == ((2 * (P)) & 15)) {                                   \
            const int rsel = l15 & 1;                                           \
            const char* gb = myScr + ((P) & 1) * 2048 + rsel * 1024;            \
            _Pragma("unroll")                                                   \
            for (int kk = 0; kk < 8; ++kk) {                                    \
                int B0 = kk * 128 + lg * 32 + rsel * 16;                        \
                f32x4 v0 = *(const f32x4*)(gb + (B0 & 1023));                   \
                f32x4 v1 = *(const f32x4*)(gb + ((B0 + 16) & 1023));            \
                half8 h;                                                        \
                h[0] = (_Float16)v0[0]; h[1] = (_Float16)v0[1];                 \
                h[2] = (_Float16)v0[2]; h[3] = (_Float16)v0[3];                 \
                h[4] = (_Float16)v1[0]; h[5] = (_Float16)v1[1];                 \
                h[6] = (_Float16)v1[2]; h[7] = (_Float16)v1[3];                 \
                DEST[(P) >> 3][kk] = h;                                         \
            }                                                                   \
        }                                                                       \
    }

    // ================= prologue: gather FIRST tile =================
    if (lane < 32)
        idsL[wave][lane] = idxC[min(rbaseC + wave * 32 + lane, cntC - 1)];
    GISSUE(0)
#define PSTEP(P)                                                                \
    __builtin_amdgcn_sched_barrier(0);                                          \
    GISSUE(P)                                                                   \
    __builtin_amdgcn_sched_barrier(0);                                          \
    asm volatile("s_waitcnt vmcnt(2)");                                         \
    __builtin_amdgcn_sched_barrier(0);                                          \
    REDIST((P) - 1, afragC)
    PSTEP(1) PSTEP(2) PSTEP(3) PSTEP(4) PSTEP(5) PSTEP(6) PSTEP(7)
    PSTEP(8) PSTEP(9) PSTEP(10) PSTEP(11) PSTEP(12) PSTEP(13) PSTEP(14) PSTEP(15)
#undef PSTEP
    // pair 15 left in scratch half 1; redistributed at chunk 0 (uniform path).

    // stage ids for NEXT tile (prologue's ids fully consumed above)
    if (hasNext && lane < 32)
        idsL[wave][lane] = idxN[min(rbaseN + wave * 32 + lane, cntN - 1)];

    // W1 chunk 0 + W2 chunk 0 + b1s[0]
    #pragma unroll
    for (int it = 0; it < 4; ++it)
        __builtin_amdgcn_global_load_lds(
            (const AS1 void*)(w1C + it * 4096 + tid * 16),
            (AS3 void*)(&W1sB[0][it * 4096 + tid * 16]), 16, 0, 0);
    if (wave < 2)
        __builtin_amdgcn_global_load_lds(
            (const AS1 void*)((const char*)(b1 + tC * HID) + tid * 16),
            (AS3 void*)((char*)&b1s[0][0] + tid * 16), 16, 0, 0);
    half8 w2A[2], w2B[2];
    #pragma unroll
    for (int nt = 0; nt < 2; ++nt)
        w2A[nt] = *(const half8*)(w2C + (nt * 16 + l15) * HID + lg * 8);
    __syncthreads();  // drains: pair15 gather + W1 chunk0 + b1s

    const f32x4 fzero = {0.f, 0.f, 0.f, 0.f};
    f32x4 acc2[MT][2];
    #pragma unroll
    for (int mt = 0; mt < MT; ++mt)
        #pragma unroll
        for (int nt = 0; nt < 2; ++nt)
            acc2[mt][nt] = fzero;

    int par = 0;

#define CHUNK_BODY(I, W2USE, W2FILL)                                            \
    {                                                                           \
        if ((I) == 0 && hasNext && wave < 2)                                    \
            __builtin_amdgcn_global_load_lds(                                   \
                (const AS1 void*)((const char*)b1N + tid * 16),                 \
                (AS3 void*)((char*)&b1s[par ^ 1][0] + tid * 16), 16, 0, 0);     \
        if ((I) == 0) { REDIST(15, afragC) }                                    \
        else if (hasNext) { REDIST((I) - 1, afragN) }                           \
        if ((I) < 15) {                                                         \
            const char* srcw = w1C + (size_t)((I) + 1) * CHUNK_BYTES;           \
            char* dstw = W1sB[((I) + 1) & 1];                                   \
            _Pragma("unroll")                                                   \
            for (int it = 0; it < 4; ++it)                                      \
                __builtin_amdgcn_global_load_lds(                               \
                    (const AS1 void*)(srcw + it * 4096 + tid * 16),             \
                    (AS3 void*)(dstw + it * 4096 + tid * 16), 16, 0, 0);        \
        } else if (hasNext) {                                                   \
            char* dstw = W1sB[0];                                               \
            _Pragma("unroll")                                                   \
            for (int it = 0; it < 4; ++it)                                      \
                __builtin_amdgcn_global_load_lds(                               \
                    (const AS1 void*)(w1N + it * 4096 + tid * 16),              \
                    (AS3 void*)(dstw + it * 4096 + tid * 16), 16, 0, 0);        \
        }                                                                       \
        if (hasNext) { GISSUE(I) }                                              \
        if ((I) < 15) {                                                         \
            _Pragma("unroll")                                                   \
            for (int nt = 0; nt < 2; ++nt)                                      \
                W2FILL[nt] = *(const half8*)(w2C + (nt * 16 + l15) * HID        \
                                             + ((I) + 1) * HC + lg * 8);        \
        } else if (hasNext) {                                                   \
            _Pragma("unroll")                                                   \
            for (int nt = 0; nt < 2; ++nt)                                      \
                W2FILL[nt] = *(const half8*)(w2N + (nt * 16 + l15) * HID + lg * 8); \
        }                                                                       \
        f32x4 acc1[MT][2];                                                      \
        _Pragma("unroll")                                                       \
        for (int mt = 0; mt < MT; ++mt)                                         \
            _Pragma("unroll")                                                   \
            for (int nt = 0; nt < 2; ++nt)                                      \
                acc1[mt][nt] = fzero;                                           \
        const char* cur = W1sB[(I) & 1];                                        \
        _Pragma("unroll")                                                       \
        for (int kk = 0; kk < 8; ++kk) {                                        \
            half8 bfr[2];                                                       \
            _Pragma("unroll")                                                   \
            for (int nt = 0; nt < 2; ++nt) {                                    \
                int hr = nt * 16 + l15;                                         \
                bfr[nt] = *(const half8*)(cur + hr * 512 +                      \
                            ((kk * 64 + lg * 16) ^ ((hr & 7) << 4)));           \
            }                                                                   \
            _Pragma("unroll")                                                   \
            for (int mt = 0; mt < MT; ++mt)                                     \
                _Pragma("unroll")                                               \
                for (int nt = 0; nt < 2; ++nt)                                  \
                    acc1[mt][nt] = __builtin_amdgcn_mfma_f32_16x16x32_f16(      \
                        bfr[nt], afragC[mt][kk], acc1[mt][nt], 0, 0, 0);        \
        }                                                                       \
        {                                                                       \
            f32x4 bv0 = *(const f32x4*)(&b1s[par][(I) * HC + lg * 4]);          \
            f32x4 bv1 = *(const f32x4*)(&b1s[par][(I) * HC + 16 + lg * 4]);     \
            _Pragma("unroll")                                                   \
            for (int mt = 0; mt < MT; ++mt) {                                   \
                half8 hfrag;                                                    \
                _Pragma("unroll")                                               \
                for (int j = 0; j < 4; ++j) {                                   \
                    hfrag[j]     = (_Float16)fmaxf(acc1[mt][0][j] + bv0[j], 0.f);\
                    hfrag[4 + j] = (_Float16)fmaxf(acc1[mt][1][j] + bv1[j], 0.f);\
                }                                                               \
                _Pragma("unroll")                                               \
                for (int nt = 0; nt < 2; ++nt)                                  \
                    acc2[mt][nt] = __builtin_amdgcn_mfma_f32_16x16x32_f16(      \
                        W2USE[nt], hfrag, acc2[mt][nt], 0, 0, 0);               \
            }                                                                   \
        }                                                                       \
        __syncthreads();                                                        \
    }

    // ================= persistent tile loop =================
    for (;;) {
        CHUNK_BODY(0,  w2A, w2B)  CHUNK_BODY(1,  w2B, w2A)
        CHUNK_BODY(2,  w2A, w2B)  CHUNK_BODY(3,  w2B, w2A)
        CHUNK_BODY(4,  w2A, w2B)  CHUNK_BODY(5,  w2B, w2A)
        CHUNK_BODY(6,  w2A, w2B)  CHUNK_BODY(7,  w2B, w2A)
        CHUNK_BODY(8,  w2A, w2B)  CHUNK_BODY(9,  w2B, w2A)
        CHUNK_BODY(10, w2A, w2B)  CHUNK_BODY(11, w2B, w2A)
        CHUNK_BODY(12, w2A, w2B)  CHUNK_BODY(13, w2B, w2A)
        CHUNK_BODY(14, w2A, w2B)  CHUNK_BODY(15, w2B, w2A)

        // ---- store tile C (out^T frags -> per-lane float4) ----
        {
            const int m = min(BM, cntC - rbaseC);
            f32x4 b2v[2];
            #pragma unroll
            for (int nt = 0; nt < 2; ++nt)
                b2v[nt] = *(const f32x4*)(b2 + tC * OUTD + nt * 16 + lg * 4);
            #pragma unroll
            for (int mt = 0; mt < MT; ++mt) {
                int rloc = wave * 32 + mt * 16 + l15;
                int gr = idxC[min(rbaseC + rloc, cntC - 1)];
                if (rloc < m) {
                    #pragma unroll
                    for (int nt = 0; nt < 2; ++nt) {
                        f32x4 v = acc2[mt][nt] + b2v[nt];
                        __builtin_nontemporal_store(
                            v, (f32x4*)(out + (size_t)gr * OUTD + nt * 16 + lg * 4));
                    }
                }
            }
            #pragma unroll
            for (int mt = 0; mt < MT; ++mt)
                #pragma unroll
                for (int nt = 0; nt < 2; ++nt)
                    acc2[mt][nt] = fzero;
        }

        if (!hasNext) break;

        // ---- advance: current <- next; decode new next; stage its ids ----
        tC = tN; cntC = cntN; rbaseC = rbaseN;
        idxC = idxN; w1C = w1N; w2C = w2N;
        par ^= 1;
        tileN += GRID_X;
        hasNext = tileN < ntiles;
        if (hasNext) {
            tN = (tileN >= meta[9]) + (tileN >= meta[10]) + (tileN >= meta[11]);
            cntN = meta[tN];
            rbaseN = (tileN - meta[8 + tN]) * BM;
            idxN = idx + meta[4 + tN];
            w1N = (const char*)(W1T + (size_t)tN * HID * DM);
            w2N = W2T + (size_t)tN * OUTD * HID;
            b1N = b1 + tN * HID;
            if (lane < 32)
                idsL[wave][lane] = idxN[min(rbaseN + wave * 32 + lane, cntN - 1)];
        }

        // afragC <- afragN (rows 0..29 valid; 30,31 completed at next chunk 0)
        #pragma unroll
        for (int mt = 0; mt < MT; ++mt)
            #pragma unroll
            for (int kk = 0; kk < 8; ++kk)
                afragC[mt][kk] = afragN[mt][kk];
    }
#undef CHUNK_BODY
#undef GISSUE
#undef REDIST
}

// ---------------- launch ----------------

extern "C" void kernel_launch(void* const* d_in, const int* in_sizes, int n_in,
                              void* d_out, int out_size, void* d_ws, size_t ws_size,
                              hipStream_t stream) {
    const float* x   = (const float*)d_in[0];
    const int* types = (const int*)d_in[1];
    const float* W1  = (const float*)d_in[2];
    const float* b1  = (const float*)d_in[3];
    const float* W2  = (const float*)d_in[4];
    const float* b2  = (const float*)d_in[5];
    float* out = (float*)d_out;

    char* ws = (char*)d_ws;
    int* meta = (int*)ws;                       // counts/offsets/tileoffs (13 ints)
    int* idx = (int*)(ws + 64);                 // N_TOK int32
    _Float16* W1T = (_Float16*)(ws + 64 + 4 * (size_t)N_TOK);
    _Float16* W2T = W1T + (size_t)NTYPE * HID * DM;
    // bc/bb alias the W1T region: used only BEFORE wprep_kernel writes W1T.
    int* bc = (int*)W1T;                        // [4][512]
    int* bb = bc + NTYPE * NBLK;                // [4][512]

    count_kernel<<<NBLK, 256, 0, stream>>>(types, bc);
    scan_blocks_kernel<<<1, 256, 0, stream>>>(bc, bb, meta);
    scatter2_kernel<<<NBLK, 256, 0, stream>>>(types, bb, idx);
    wprep_kernel<<<(NTYPE * HID * DM) / 256, 256, 0, stream>>>(W1, W2, W1T, W2T);

    fused_mlp_kernel<<<GRID_X, 256, 0, stream>>>(x, meta, idx, W1T, W2T, b1, b2, out);
}

// Round 13
// 372.538 us; speedup vs baseline: 1.0047x; 1.0047x over previous
//
#include <hip/hip_runtime.h>
#include <hip/hip_bf16.h>
#include <hip/hip_fp16.h>

#define N_TOK 524288
#define DM 256
#define HID 512
#define OUTD 32
#define NTYPE 4
#define BM 128                     // rows per tile (32/wave, mt=2)
#define MT 2
#define HC 32
#define NCHUNK (HID / HC)          // 16
#define CHUNK_BYTES (HC * DM * 2)  // 16384
#define NBLK 512                   // partition blocks; N_TOK = NBLK * 1024
#define GRID_X 512                 // persistent blocks: 2/CU x 256 CU

typedef _Float16 half8 __attribute__((ext_vector_type(8)));
typedef float f32x4 __attribute__((ext_vector_type(4)));

#define AS1 __attribute__((address_space(1)))
#define AS3 __attribute__((address_space(3)))

// ---------------- deterministic atomic-free partition ----------------

__global__ void count_kernel(const int* __restrict__ types, int* __restrict__ bc) {
    __shared__ int c[NTYPE];
    int tid = threadIdx.x;
    if (tid < NTYPE) c[tid] = 0;
    __syncthreads();
    int b = blockIdx.x;
    int lane = tid & 63;
    #pragma unroll
    for (int j = 0; j < 4; ++j) {
        int t = types[b * 1024 + j * 256 + tid];
        #pragma unroll
        for (int tt = 0; tt < NTYPE; ++tt) {
            unsigned long long mask = __ballot(t == tt);
            if (lane == 0) atomicAdd(&c[tt], __popcll(mask));
        }
    }
    __syncthreads();
    if (tid < NTYPE) bc[tid * NBLK + b] = c[tid];
}

// meta: [0..3] counts, [4..7] row offsets, [8..11] tile offsets, [12] total tiles
__global__ void scan_blocks_kernel(const int* __restrict__ bc,
                                   int* __restrict__ bb,
                                   int* __restrict__ meta) {
    __shared__ int totals[NTYPE];
    __shared__ int typeoff[NTYPE];
    int wave = threadIdx.x >> 6, lane = threadIdx.x & 63;
    int excl[NBLK / 64];
    int running = 0;
    #pragma unroll
    for (int it = 0; it < NBLK / 64; ++it) {
        int v = bc[wave * NBLK + it * 64 + lane];
        int s = v;
        #pragma unroll
        for (int d = 1; d < 64; d <<= 1) {
            int u = __shfl_up(s, d);
            if (lane >= d) s += u;
        }
        excl[it] = running + s - v;
        running += __shfl(s, 63);
    }
    if (lane == 0) totals[wave] = running;
    __syncthreads();
    if (threadIdx.x == 0) {
        int off = 0, toff = 0;
        for (int tt = 0; tt < NTYPE; ++tt) {
            typeoff[tt] = off;
            meta[tt] = totals[tt];
            meta[4 + tt] = off;
            meta[8 + tt] = toff;
            off += totals[tt];
            toff += (totals[tt] + BM - 1) / BM;
        }
        meta[12] = toff;
    }
    __syncthreads();
    #pragma unroll
    for (int it = 0; it < NBLK / 64; ++it)
        bb[wave * NBLK + it * 64 + lane] = typeoff[wave] + excl[it];
}

__global__ void scatter2_kernel(const int* __restrict__ types,
                                const int* __restrict__ bb,
                                int* __restrict__ idx) {
    __shared__ int base[NTYPE];
    __shared__ int wcnt[4][NTYPE];
    int b = blockIdx.x;
    int tid = threadIdx.x, wave = tid >> 6, lane = tid & 63;
    if (tid < NTYPE) base[tid] = bb[tid * NBLK + b];
    #pragma unroll
    for (int j = 0; j < 4; ++j) {
        __syncthreads();
        int i = b * 1024 + j * 256 + tid;
        int t = types[i];
        int rank = 0;
        #pragma unroll
        for (int tt = 0; tt < NTYPE; ++tt) {
            unsigned long long mask = __ballot(t == tt);
            if (t == tt) rank = __popcll(mask & ((1ull << lane) - 1ull));
            if (lane == 0) wcnt[wave][tt] = __popcll(mask);
        }
        __syncthreads();
        int pre = 0;
        for (int w = 0; w < wave; ++w) pre += wcnt[w][t];
        idx[base[t] + pre + rank] = i;
        __syncthreads();
        if (tid < NTYPE) {
            int tot = 0;
            #pragma unroll
            for (int w = 0; w < 4; ++w) tot += wcnt[w][tid];
            base[tid] += tot;
        }
    }
}

// ---------------- weight prep (unchanged) ----------------

__global__ void wprep_kernel(const float* __restrict__ W1, const float* __restrict__ W2,
                             _Float16* __restrict__ W1T, _Float16* __restrict__ W2T) {
    int i = blockIdx.x * blockDim.x + threadIdx.x;
    if (i < NTYPE * HID * DM) {
        int t = i / (HID * DM);
        int r = i - t * (HID * DM);
        int byteoff = r * 2;
        int hc = byteoff / CHUNK_BYTES;
        int rem = byteoff - hc * CHUNK_BYTES;
        int hr = rem >> 9;
        int brow = rem & 511;
        int d = (brow ^ ((hr & 7) << 4)) >> 1;
        int h = hc * HC + hr;
        W1T[i] = (_Float16)W1[(t * DM + d) * HID + h];
    }
    if (i < NTYPE * OUTD * HID) {
        int t = i / (OUTD * HID);
        int r = i - t * (OUTD * HID);
        int o = r / HID;
        int pg = r - o * HID;
        int hc = pg >> 5;
        int p = pg & 31;
        int lg = p >> 3, j = p & 7;
        int h1 = (j < 4) ? (lg * 4 + j) : (16 + lg * 4 + (j - 4));
        int h = hc * HC + h1;
        W2T[i] = (_Float16)W2[(t * HID + h) * OUTD + o];
    }
}

// ---------------- persistent fused MLP with cross-tile gather pipeline ------
// 512 blocks (2/CU), each ~8 tiles. During tile k's 16 chunks, 2 rows/chunk of
// tile k+1 are gather-DMA'd into wave-private scratch and redistributed into
// afragN one chunk later; chunk 15 prefetches next tile's W1 chunk0 / W2 / b1.
// => HBM gather traffic flows during EVERY chunk instead of in a serial
// prologue (R11's ~50% HBM duty was the bottleneck).

__launch_bounds__(256)
__global__ void fused_mlp_kernel(const float* __restrict__ x,
                                 const int* __restrict__ meta,
                                 const int* __restrict__ idx,
                                 const _Float16* __restrict__ W1T,
                                 const _Float16* __restrict__ W2T,
                                 const float* __restrict__ b1,
                                 const float* __restrict__ b2,
                                 float* __restrict__ out) {
    __shared__ __align__(16) char W1sB[2][CHUNK_BYTES];  // 32 KB W1 double buffer
    __shared__ __align__(16) char scr[4][2][2048];       // 16 KB gather scratch (per wave)
    __shared__ __align__(16) float b1s[2][HID];          // 4 KB bias, tile-parity dbuf
    __shared__ int idsL[4][32];                          // next tile's row ids per wave

    const int ntiles = meta[12];
    int tile = blockIdx.x;
    if (tile >= ntiles) return;

    const int tid = threadIdx.x;
    const int wave = tid >> 6;
    const int lane = tid & 63;
    const int l15 = lane & 15;
    const int lg = lane >> 4;
    char* myScr = &scr[wave][0][0];

    // ---- decode current tile ----
    int tC = (tile >= meta[9]) + (tile >= meta[10]) + (tile >= meta[11]);
    int cntC = meta[tC];
    int rbaseC = (tile - meta[8 + tC]) * BM;
    const int* idxC = idx + meta[4 + tC];
    const char* w1C = (const char*)(W1T + (size_t)tC * HID * DM);
    const _Float16* w2C = W2T + (size_t)tC * OUTD * HID;

    // ---- decode next tile ----
    int tileN = tile + GRID_X;
    bool hasNext = tileN < ntiles;
    int tN = 0, cntN = 1, rbaseN = 0;
    const int* idxN = idx;
    const char* w1N = w1C;
    const _Float16* w2N = w2C;
    const float* b1N = b1;
    if (hasNext) {
        tN = (tileN >= meta[9]) + (tileN >= meta[10]) + (tileN >= meta[11]);
        cntN = meta[tN];
        rbaseN = (tileN - meta[8 + tN]) * BM;
        idxN = idx + meta[4 + tN];
        w1N = (const char*)(W1T + (size_t)tN * HID * DM);
        w2N = W2T + (size_t)tN * OUTD * HID;
        b1N = b1 + tN * HID;
    }

    half8 afragC[MT][8], afragN[MT][8];

// issue gather pair P (rows 2P,2P+1 of the NEXT tile) into scratch half P&1.
// row i source rotated by ((lane-i)&63)*16 so both rows' redistribute reads
// spread banks; LDS dest is wave-uniform base + lane*16 (DMA requirement).
#define GISSUE(P)                                                               \
    {                                                                           \
        int2 rid = *(const int2*)&idsL[wave][2 * (P)];                          \
        const char* s0 = (const char*)(x + (size_t)rid.x * DM) + lane * 16;     \
        const char* s1 = (const char*)(x + (size_t)rid.y * DM)                  \
                         + ((lane - 1) & 63) * 16;                              \
        __builtin_amdgcn_global_load_lds((const AS1 void*)s0,                   \
            (AS3 void*)(myScr + ((P) & 1) * 2048 + lane * 16), 16, 0, 0);       \
        __builtin_amdgcn_global_load_lds((const AS1 void*)s1,                   \
            (AS3 void*)(myScr + ((P) & 1) * 2048 + 1024 + lane * 16), 16, 0, 0);\
    }

// redistribute pair P from scratch half P&1 into DEST regs (8 active lanes:
// l15 in {2P&15, (2P&15)+1}, all lg). Rotation undone via (B + rsel*16)&1023.
#define REDIST(P, DEST)                                                         \
    {                                                                           \
        if ((l15 & 14) == ((2 * (P)) & 15)) {                                   \
            const int rsel = l15 & 1;                                           \
            const char* gb = myScr + ((P) & 1) * 2048 + rsel * 1024;            \
            _Pragma("unroll")                                                   \
            for (int kk = 0; kk < 8; ++kk) {                                    \
                int B0 = kk * 128 + lg * 32 + rsel * 16;                        \
                f32x4 v0 = *(const f32x4*)(gb + (B0 & 1023));                   \
                f32x4 v1 = *(const f32x4*)(gb + ((B0 + 16) & 1023));            \
                half8 h;                                                        \
                h[0] = (_Float16)v0[0]; h[1] = (_Float16)v0[1];                 \
                h[2] = (_Float16)v0[2]; h[3] = (_Float16)v0[3];                 \
                h[4] = (_Float16)v1[0]; h[5] = (_Float16)v1[1];                 \
                h[6] = (_Float16)v1[2]; h[7] = (_Float16)v1[3];                 \
                DEST[(P) >> 3][kk] = h;                                         \
            }                                                                   \
        }                                                                       \
    }

    // ================= prologue: gather FIRST tile =================
    if (lane < 32)
        idsL[wave][lane] = idxC[min(rbaseC + wave * 32 + lane, cntC - 1)];
    GISSUE(0)
#define PSTEP(P)                                                                \
    __builtin_amdgcn_sched_barrier(0);                                          \
    GISSUE(P)                                                                   \
    __builtin_amdgcn_sched_barrier(0);                                          \
    asm volatile("s_waitcnt vmcnt(2)");                                         \
    __builtin_amdgcn_sched_barrier(0);                                          \
    REDIST((P) - 1, afragC)
    PSTEP(1) PSTEP(2) PSTEP(3) PSTEP(4) PSTEP(5) PSTEP(6) PSTEP(7)
    PSTEP(8) PSTEP(9) PSTEP(10) PSTEP(11) PSTEP(12) PSTEP(13) PSTEP(14) PSTEP(15)
#undef PSTEP
    // pair 15 left in scratch half 1; redistributed at chunk 0 (uniform path).

    // stage ids for NEXT tile (prologue's ids fully consumed above)
    if (hasNext && lane < 32)
        idsL[wave][lane] = idxN[min(rbaseN + wave * 32 + lane, cntN - 1)];

    // W1 chunk 0 + W2 chunk 0 + b1s[0]
    #pragma unroll
    for (int it = 0; it < 4; ++it)
        __builtin_amdgcn_global_load_lds(
            (const AS1 void*)(w1C + it * 4096 + tid * 16),
            (AS3 void*)(&W1sB[0][it * 4096 + tid * 16]), 16, 0, 0);
    if (wave < 2)
        __builtin_amdgcn_global_load_lds(
            (const AS1 void*)((const char*)(b1 + tC * HID) + tid * 16),
            (AS3 void*)((char*)&b1s[0][0] + tid * 16), 16, 0, 0);
    half8 w2A[2], w2B[2];
    #pragma unroll
    for (int nt = 0; nt < 2; ++nt)
        w2A[nt] = *(const half8*)(w2C + (nt * 16 + l15) * HID + lg * 8);
    __syncthreads();  // drains: pair15 gather + W1 chunk0 + b1s

    const f32x4 fzero = {0.f, 0.f, 0.f, 0.f};
    f32x4 acc2[MT][2];
    #pragma unroll
    for (int mt = 0; mt < MT; ++mt)
        #pragma unroll
        for (int nt = 0; nt < 2; ++nt)
            acc2[mt][nt] = fzero;

    int par = 0;

#define CHUNK_BODY(I, W2USE, W2FILL)                                            \
    {                                                                           \
        if ((I) == 0 && hasNext && wave < 2)                                    \
            __builtin_amdgcn_global_load_lds(                                   \
                (const AS1 void*)((const char*)b1N + tid * 16),                 \
                (AS3 void*)((char*)&b1s[par ^ 1][0] + tid * 16), 16, 0, 0);     \
        if ((I) == 0) { REDIST(15, afragC) }                                    \
        else if (hasNext) { REDIST((I) - 1, afragN) }                           \
        if ((I) < 15) {                                                         \
            const char* srcw = w1C + (size_t)((I) + 1) * CHUNK_BYTES;           \
            char* dstw = W1sB[((I) + 1) & 1];                                   \
            _Pragma("unroll")                                                   \
            for (int it = 0; it < 4; ++it)                                      \
                __builtin_amdgcn_global_load_lds(                               \
                    (const AS1 void*)(srcw + it * 4096 + tid * 16),             \
                    (AS3 void*)(dstw + it * 4096 + tid * 16), 16, 0, 0);        \
        } else if (hasNext) {                                                   \
            char* dstw = W1sB[0];                                               \
            _Pragma("unroll")                                                   \
            for (int it = 0; it < 4; ++it)                                      \
                __builtin_amdgcn_global_load_lds(                               \
                    (const AS1 void*)(w1N + it * 4096 + tid * 16),              \
                    (AS3 void*)(dstw + it * 4096 + tid * 16), 16, 0, 0);        \
        }                                                                       \
        if (hasNext) { GISSUE(I) }                                              \
        if ((I) < 15) {                                                         \
            _Pragma("unroll")                                                   \
            for (int nt = 0; nt < 2; ++nt)                                      \
                W2FILL[nt] = *(const half8*)(w2C + (nt * 16 + l15) * HID        \
                                             + ((I) + 1) * HC + lg * 8);        \
        } else if (hasNext) {                                                   \
            _Pragma("unroll")                                                   \
            for (int nt = 0; nt < 2; ++nt)                                      \
                W2FILL[nt] = *(const half8*)(w2N + (nt * 16 + l15) * HID + lg * 8); \
        }                                                                       \
        f32x4 acc1[MT][2];                                                      \
        _Pragma("unroll")                                                       \
        for (int mt = 0; mt < MT; ++mt)                                         \
            _Pragma("unroll")                                                   \
            for (int nt = 0; nt < 2; ++nt)                                      \
                acc1[mt][nt] = fzero;                                           \
        const char* cur = W1sB[(I) & 1];                                        \
        _Pragma("unroll")                                                       \
        for (int kk = 0; kk < 8; ++kk) {                                        \
            half8 bfr[2];                                                       \
            _Pragma("unroll")                                                   \
            for (int nt = 0; nt < 2; ++nt) {                                    \
                int hr = nt * 16 + l15;                                         \
                bfr[nt] = *(const half8*)(cur + hr * 512 +                      \
                            ((kk * 64 + lg * 16) ^ ((hr & 7) << 4)));           \
            }                                                                   \
            _Pragma("unroll")                                                   \
            for (int mt = 0; mt < MT; ++mt)                                     \
                _Pragma("unroll")                                               \
                for (int nt = 0; nt < 2; ++nt)                                  \
                    acc1[mt][nt] = __builtin_amdgcn_mfma_f32_16x16x32_f16(      \
                        bfr[nt], afragC[mt][kk], acc1[mt][nt], 0, 0, 0);        \
        }                                                                       \
        {                                                                       \
            f32x4 bv0 = *(const f32x4*)(&b1s[par][(I) * HC + lg * 4]);          \
            f32x4 bv1 = *(const f32x4*)(&b1s[par][(I) * HC + 16 + lg * 4]);     \
            _Pragma("unroll")                                                   \
            for (int mt = 0; mt < MT; ++mt) {                                   \
                half8 hfrag;                                                    \
                _Pragma("unroll")                                               \
                for (int j = 0; j < 4; ++j) {                                   \
                    hfrag[j]     = (_Float16)fmaxf(acc1[mt][0][j] + bv0[j], 0.f);\
                    hfrag[4 + j] = (_Float16)fmaxf(acc1[mt][1][j] + bv1[j], 0.f);\
                }                                                               \
                _Pragma("unroll")                                               \
                for (int nt = 0; nt < 2; ++nt)                                  \
                    acc2[mt][nt] = __builtin_amdgcn_mfma_f32_16x16x32_f16(      \
                        W2USE[nt], hfrag, acc2[mt][nt], 0, 0, 0);               \
            }                                                                   \
        }                                                                       \
        __syncthreads();                                                        \
    }

    // ================= persistent tile loop =================
    for (;;) {
        CHUNK_BODY(0,  w2A, w2B)  CHUNK_BODY(1,  w2B, w2A)
        CHUNK_BODY(2,  w2A, w2B)  CHUNK_BODY(3,  w2B, w2A)
        CHUNK_BODY(4,  w2A, w2B)  CHUNK_BODY(5,  w2B, w2A)
        CHUNK_BODY(6,  w2A, w2B)  CHUNK_BODY(7,  w2B, w2A)
        CHUNK_BODY(8,  w2A, w2B)  CHUNK_BODY(9,  w2B, w2A)
        CHUNK_BODY(10, w2A, w2B)  CHUNK_BODY(11, w2B, w2A)
        CHUNK_BODY(12, w2A, w2B)  CHUNK_BODY(13, w2B, w2A)
        CHUNK_BODY(14, w2A, w2B)  CHUNK_BODY(15, w2B, w2A)

        // ---- store tile C (out^T frags -> per-lane float4) ----
        {
            const int m = min(BM, cntC - rbaseC);
            f32x4 b2v[2];
            #pragma unroll
            for (int nt = 0; nt < 2; ++nt)
                b2v[nt] = *(const f32x4*)(b2 + tC * OUTD + nt * 16 + lg * 4);
            #pragma unroll
            for (int mt = 0; mt < MT; ++mt) {
                int rloc = wave * 32 + mt * 16 + l15;
                int gr = idxC[min(rbaseC + rloc, cntC - 1)];
                if (rloc < m) {
                    #pragma unroll
                    for (int nt = 0; nt < 2; ++nt) {
                        f32x4 v = acc2[mt][nt] + b2v[nt];
                        __builtin_nontemporal_store(
                            v, (f32x4*)(out + (size_t)gr * OUTD + nt * 16 + lg * 4));
                    }
                }
            }
            #pragma unroll
            for (int mt = 0; mt < MT; ++mt)
                #pragma unroll
                for (int nt = 0; nt < 2; ++nt)
                    acc2[mt][nt] = fzero;
        }

        if (!hasNext) break;

        // ---- advance: current <- next; decode new next; stage its ids ----
        tC = tN; cntC = cntN; rbaseC = rbaseN;
        idxC = idxN; w1C = w1N; w2C = w2N;
        par ^= 1;
        tileN += GRID_X;
        hasNext = tileN < ntiles;
        if (hasNext) {
            tN = (tileN >= meta[9]) + (tileN >= meta[10]) + (tileN >= meta[11]);
            cntN = meta[tN];
            rbaseN = (tileN - meta[8 + tN]) * BM;
            idxN = idx + meta[4 + tN];
            w1N = (const char*)(W1T + (size_t)tN * HID * DM);
            w2N = W2T + (size_t)tN * OUTD * HID;
            b1N = b1 + tN * HID;
            if (lane < 32)
                idsL[wave][lane] = idxN[min(rbaseN + wave * 32 + lane, cntN - 1)];
        }

        // afragC <- afragN (rows 0..29 valid; 30,31 completed at next chunk 0)
        #pragma unroll
        for (int mt = 0; mt < MT; ++mt)
            #pragma unroll
            for (int kk = 0; kk < 8; ++kk)
                afragC[mt][kk] = afragN[mt][kk];
    }
#undef CHUNK_BODY
#undef GISSUE
#undef REDIST
}

// ---------------- launch ----------------

extern "C" void kernel_launch(void* const* d_in, const int* in_sizes, int n_in,
                              void* d_out, int out_size, void* d_ws, size_t ws_size,
                              hipStream_t stream) {
    const float* x   = (const float*)d_in[0];
    const int* types = (const int*)d_in[1];
    const float* W1  = (const float*)d_in[2];
    const float* b1  = (const float*)d_in[3];
    const float* W2  = (const float*)d_in[4];
    const float* b2  = (const float*)d_in[5];
    float* out = (float*)d_out;

    char* ws = (char*)d_ws;
    int* meta = (int*)ws;                       // counts/offsets/tileoffs (13 ints)
    int* idx = (int*)(ws + 64);                 // N_TOK int32
    _Float16* W1T = (_Float16*)(ws + 64 + 4 * (size_t)N_TOK);
    _Float16* W2T = W1T + (size_t)NTYPE * HID * DM;
    // bc/bb alias the W1T region: used only BEFORE wprep_kernel writes W1T.
    int* bc = (int*)W1T;                        // [4][512]
    int* bb = bc + NTYPE * NBLK;                // [4][512]

    count_kernel<<<NBLK, 256, 0, stream>>>(types, bc);
    scan_blocks_kernel<<<1, 256, 0, stream>>>(bc, bb, meta);
    scatter2_kernel<<<NBLK, 256, 0, stream>>>(types, bb, idx);
    wprep_kernel<<<(NTYPE * HID * DM) / 256, 256, 0, stream>>>(W1, W2, W1T, W2T);

    fused_mlp_kernel<<<GRID_X, 256, 0, stream>>>(x, meta, idx, W1T, W2T, b1, b2, out);
}

// Round 14
// 269.487 us; speedup vs baseline: 1.3889x; 1.3824x over previous
//
#include <hip/hip_runtime.h>
#include <hip/hip_bf16.h>
#include <hip/hip_fp16.h>

#define N_TOK 524288
#define DM 256
#define HID 512
#define OUTD 32
#define NTYPE 4
#define BM 128                     // rows per block (mt=2 per wave, 32 rows/wave)
#define MT 2
#define HC 32
#define NCHUNK (HID / HC)          // 16
#define CHUNK_BYTES (HC * DM * 2)  // 16384
#define NBLK 512                   // partition blocks; N_TOK = NBLK * 1024
#define GX1D (N_TOK / BM + NTYPE)  // exact tiles + per-type ceil slack

typedef _Float16 half8 __attribute__((ext_vector_type(8)));
typedef float f32x4 __attribute__((ext_vector_type(4)));

#define AS1 __attribute__((address_space(1)))
#define AS3 __attribute__((address_space(3)))

// ---------------- deterministic atomic-free partition ----------------

__global__ void count_kernel(const int* __restrict__ types, int* __restrict__ bc) {
    __shared__ int c[NTYPE];
    int tid = threadIdx.x;
    if (tid < NTYPE) c[tid] = 0;
    __syncthreads();
    int b = blockIdx.x;
    int lane = tid & 63;
    #pragma unroll
    for (int j = 0; j < 4; ++j) {
        int t = types[b * 1024 + j * 256 + tid];
        #pragma unroll
        for (int tt = 0; tt < NTYPE; ++tt) {
            unsigned long long mask = __ballot(t == tt);
            if (lane == 0) atomicAdd(&c[tt], __popcll(mask));
        }
    }
    __syncthreads();
    if (tid < NTYPE) bc[tid * NBLK + b] = c[tid];
}

// meta: [0..3] counts, [4..7] row offsets, [8..11] tile offsets, [12] total tiles
__global__ void scan_blocks_kernel(const int* __restrict__ bc,
                                   int* __restrict__ bb,
                                   int* __restrict__ meta) {
    __shared__ int totals[NTYPE];
    __shared__ int typeoff[NTYPE];
    int wave = threadIdx.x >> 6, lane = threadIdx.x & 63;
    int excl[NBLK / 64];
    int running = 0;
    #pragma unroll
    for (int it = 0; it < NBLK / 64; ++it) {
        int v = bc[wave * NBLK + it * 64 + lane];
        int s = v;
        #pragma unroll
        for (int d = 1; d < 64; d <<= 1) {
            int u = __shfl_up(s, d);
            if (lane >= d) s += u;
        }
        excl[it] = running + s - v;
        running += __shfl(s, 63);
    }
    if (lane == 0) totals[wave] = running;
    __syncthreads();
    if (threadIdx.x == 0) {
        int off = 0, toff = 0;
        for (int tt = 0; tt < NTYPE; ++tt) {
            typeoff[tt] = off;
            meta[tt] = totals[tt];
            meta[4 + tt] = off;
            meta[8 + tt] = toff;
            off += totals[tt];
            toff += (totals[tt] + BM - 1) / BM;
        }
        meta[12] = toff;
    }
    __syncthreads();
    #pragma unroll
    for (int it = 0; it < NBLK / 64; ++it)
        bb[wave * NBLK + it * 64 + lane] = typeoff[wave] + excl[it];
}

__global__ void scatter2_kernel(const int* __restrict__ types,
                                const int* __restrict__ bb,
                                int* __restrict__ idx) {
    __shared__ int base[NTYPE];
    __shared__ int wcnt[4][NTYPE];
    int b = blockIdx.x;
    int tid = threadIdx.x, wave = tid >> 6, lane = tid & 63;
    if (tid < NTYPE) base[tid] = bb[tid * NBLK + b];
    #pragma unroll
    for (int j = 0; j < 4; ++j) {
        __syncthreads();
        int i = b * 1024 + j * 256 + tid;
        int t = types[i];
        int rank = 0;
        #pragma unroll
        for (int tt = 0; tt < NTYPE; ++tt) {
            unsigned long long mask = __ballot(t == tt);
            if (t == tt) rank = __popcll(mask & ((1ull << lane) - 1ull));
            if (lane == 0) wcnt[wave][tt] = __popcll(mask);
        }
        __syncthreads();
        int pre = 0;
        for (int w = 0; w < wave; ++w) pre += wcnt[w][t];
        idx[base[t] + pre + rank] = i;
        __syncthreads();
        if (tid < NTYPE) {
            int tot = 0;
            #pragma unroll
            for (int w = 0; w < 4; ++w) tot += wcnt[w][tid];
            base[tid] += tot;
        }
    }
}

// ---------------- weight prep ----------------
// W1T: per type, 16 chunks of [32 h][256 d] f16, rows XOR-swizzled
// (byte_in_row = (d*2) ^ ((hr&7)<<4)), stored linearly in global_load_lds
// write order (inverse-swizzled source + swizzled read).
// W2T: [t][o][p] f16 with hidden dim PERMUTED per 32-chunk so the swapped-
// GEMM1 register output layout (h = nt*16 + lg*4 + j) is exactly the K=32
// B-operand slot order (p = lg*8 + j): p -> h1 = j<4 ? lg*4+j : 16+lg*4+(j-4)

__global__ void wprep_kernel(const float* __restrict__ W1, const float* __restrict__ W2,
                             _Float16* __restrict__ W1T, _Float16* __restrict__ W2T) {
    int i = blockIdx.x * blockDim.x + threadIdx.x;
    if (i < NTYPE * HID * DM) {
        int t = i / (HID * DM);
        int r = i - t * (HID * DM);
        int byteoff = r * 2;
        int hc = byteoff / CHUNK_BYTES;
        int rem = byteoff - hc * CHUNK_BYTES;
        int hr = rem >> 9;
        int brow = rem & 511;
        int d = (brow ^ ((hr & 7) << 4)) >> 1;
        int h = hc * HC + hr;
        W1T[i] = (_Float16)W1[(t * DM + d) * HID + h];
    }
    if (i < NTYPE * OUTD * HID) {
        int t = i / (OUTD * HID);
        int r = i - t * (OUTD * HID);
        int o = r / HID;
        int pg = r - o * HID;          // permuted k position
        int hc = pg >> 5;
        int p = pg & 31;
        int lg = p >> 3, j = p & 7;
        int h1 = (j < 4) ? (lg * 4 + j) : (16 + lg * 4 + (j - 4));
        int h = hc * HC + h1;
        W2T[i] = (_Float16)W2[(t * HID + h) * OUTD + o];
    }
}

// ---------------- fused grouped MLP (coalesced gather + 2-ahead W1 DMA) -----
// 256 threads = 4 waves; block = 128 gathered rows of one type (32/wave).
// GATHER (unchanged from R11): per row one global_load_lds reads the full
// 1 KB row contiguously (per-lane source rotated), redistributed to regs.
// CHUNK LOOP (new): W1 TRIPLE buffer, DMA issued 2 chunks ahead -> ~2 chunks
// (~800+ cyc) of latency slack instead of 1 (R10's counted-vmcnt null: the
// 1-chunk budget was < DMA latency). Barrier = counted vmcnt + raw s_barrier.
// CRITICAL ordering: W2 prefetch is issued BEFORE the W1 DMA each chunk, so
// GEMM2's implicit wait on W2 is vmcnt(10) (leaves DMAs in flight), not a
// drain. Steady-state in-flight at barrier: [W2(2), DMA(4)] -> vmcnt(6).
// Buffers: read I%3, write (I+2)%3, in-flight (I+1)%3 -- pairwise distinct;
// (I+2)%3 readers passed the previous barrier.

__launch_bounds__(256)
__global__ void fused_mlp_kernel(const float* __restrict__ x,
                                 const int* __restrict__ meta,
                                 const int* __restrict__ idx,
                                 const _Float16* __restrict__ W1T,
                                 const _Float16* __restrict__ W2T,
                                 const float* __restrict__ b1,
                                 const float* __restrict__ b2,
                                 float* __restrict__ out) {
    const int b = blockIdx.x;
    if (b >= meta[12]) return;
    const int t = (b >= meta[9]) + (b >= meta[10]) + (b >= meta[11]);
    const int cnt = meta[t];
    const int row_base = (b - meta[8 + t]) * BM;
    const int* idx_t = idx + meta[4 + t];

    __shared__ __align__(16) char W1sB[3][CHUNK_BYTES];  // 48 KB triple buffer
    __shared__ __align__(16) float b1s[HID];             // 2 KB

    const int tid = threadIdx.x;
    const int wave = tid >> 6;
    const int lane = tid & 63;
    const int l15 = lane & 15;
    const int lg = lane >> 4;

    // bias -> LDS (before any gather DMA; its compiler vmcnt wait lands here)
    {
        float2 bv = *(const float2*)(b1 + t * HID + tid * 2);
        b1s[tid * 2] = bv.x;
        b1s[tid * 2 + 1] = bv.y;
    }
    __builtin_amdgcn_sched_barrier(0);

    // preload this wave's 32 row ids (keeps the gather vmcnt count exact)
    int rg[32];
    #pragma unroll
    for (int r = 0; r < 32; ++r)
        rg[r] = idx_t[min(row_base + wave * 32 + r, cnt - 1)];
    __builtin_amdgcn_sched_barrier(0);

    // ---- coalesced gather: 32 rows/wave, 8 groups of 4, 2-deep dbuf ----
    half8 afrag[MT][8];
    char* scratch = &W1sB[0][0] + wave * 8192;   // 2 x 4 KB halves (buf0+buf1 area)

#define ISSUE_GROUP(G)                                                          \
    {                                                                           \
        _Pragma("unroll")                                                       \
        for (int i = 0; i < 4; ++i) {                                           \
            const char* src = (const char*)(x + (size_t)rg[(G) * 4 + i] * DM)   \
                              + ((lane - i) & 63) * 16;                         \
            __builtin_amdgcn_global_load_lds(                                   \
                (const AS1 void*)src,                                           \
                (AS3 void*)(scratch + ((G) & 1) * 4096 + i * 1024), 16, 0, 0);  \
        }                                                                       \
    }

    ISSUE_GROUP(0)
#define GATHER_GROUP(G)                                                         \
    {                                                                           \
        if ((G) < 7) { __builtin_amdgcn_sched_barrier(0); ISSUE_GROUP((G) + 1) }\
        if ((G) < 7) asm volatile("s_waitcnt vmcnt(4)");                        \
        else         asm volatile("s_waitcnt vmcnt(0)");                        \
        __builtin_amdgcn_sched_barrier(0);                                      \
        if ((l15 >> 2) == ((G) & 3)) {                                          \
            const int r3 = l15 & 3;                                             \
            const char* gb = scratch + ((G) & 1) * 4096 + r3 * 1024;            \
            _Pragma("unroll")                                                   \
            for (int kk = 0; kk < 8; ++kk) {                                    \
                int B0 = kk * 128 + lg * 32;                                    \
                f32x4 v0 = *(const f32x4*)(gb + ((B0 + r3 * 16) & 1023));       \
                f32x4 v1 = *(const f32x4*)(gb + ((B0 + 16 + r3 * 16) & 1023));  \
                half8 h;                                                        \
                h[0] = (_Float16)v0[0]; h[1] = (_Float16)v0[1];                 \
                h[2] = (_Float16)v0[2]; h[3] = (_Float16)v0[3];                 \
                h[4] = (_Float16)v1[0]; h[5] = (_Float16)v1[1];                 \
                h[6] = (_Float16)v1[2]; h[7] = (_Float16)v1[3];                 \
                afrag[(G) >> 2][kk] = h;                                        \
            }                                                                   \
        }                                                                       \
    }

    GATHER_GROUP(0) GATHER_GROUP(1) GATHER_GROUP(2) GATHER_GROUP(3)
    GATHER_GROUP(4) GATHER_GROUP(5) GATHER_GROUP(6) GATHER_GROUP(7)
#undef GATHER_GROUP
#undef ISSUE_GROUP

    __syncthreads();  // all waves done with W1sB-as-scratch

    const f32x4 fzero = {0.f, 0.f, 0.f, 0.f};
    f32x4 acc2[MT][2];   // out^T frags: lane holds o = nt2*16 + lg*4 + j for row l15
    #pragma unroll
    for (int mt = 0; mt < MT; ++mt)
        #pragma unroll
        for (int nt = 0; nt < 2; ++nt)
            acc2[mt][nt] = fzero;

    const char* w1base = (const char*)(W1T + (size_t)t * HID * DM);
    const _Float16* w2t_t = W2T + (size_t)t * OUTD * HID;

    // prologue: W2 chunk0 frags + W1 chunks 0 AND 1, full drain barrier
    half8 w2A[2], w2B[2];
    #pragma unroll
    for (int nt = 0; nt < 2; ++nt)
        w2A[nt] = *(const half8*)(w2t_t + (nt * 16 + l15) * HID + lg * 8);
    #pragma unroll
    for (int it = 0; it < 4; ++it)
        __builtin_amdgcn_global_load_lds(
            (const AS1 void*)(w1base + it * 4096 + tid * 16),
            (AS3 void*)(&W1sB[0][it * 4096 + tid * 16]), 16, 0, 0);
    #pragma unroll
    for (int it = 0; it < 4; ++it)
        __builtin_amdgcn_global_load_lds(
            (const AS1 void*)(w1base + CHUNK_BYTES + it * 4096 + tid * 16),
            (AS3 void*)(&W1sB[1][it * 4096 + tid * 16]), 16, 0, 0);
    __syncthreads();  // chunks 0,1 + w2A drained (one-time vmcnt0)

#define CHUNK_BODY(HCI, W2USE, W2FILL)                                          \
    {                                                                           \
        const int hc = (HCI);                                                   \
        /* W2 prefetch FIRST (oldest in flight -> GEMM2 wait != drain) */       \
        if (hc + 1 < NCHUNK) {                                                  \
            _Pragma("unroll")                                                   \
            for (int nt = 0; nt < 2; ++nt)                                      \
                W2FILL[nt] = *(const half8*)(w2t_t + (nt * 16 + l15) * HID      \
                                             + (hc + 1) * HC + lg * 8);         \
        }                                                                       \
        __builtin_amdgcn_sched_barrier(0);                                      \
        /* W1 DMA two chunks ahead into buf (hc+2)%3 */                         \
        if (hc + 2 < NCHUNK) {                                                  \
            const char* srcw = w1base + (size_t)(hc + 2) * CHUNK_BYTES;         \
            char* dstw = W1sB[(hc + 2) % 3];                                    \
            _Pragma("unroll")                                                   \
            for (int it = 0; it < 4; ++it)                                      \
                __builtin_amdgcn_global_load_lds(                               \
                    (const AS1 void*)(srcw + it * 4096 + tid * 16),             \
                    (AS3 void*)(dstw + it * 4096 + tid * 16), 16, 0, 0);        \
        }                                                                       \
        __builtin_amdgcn_sched_barrier(0);                                      \
        f32x4 acc1[MT][2];  /* H^T: lane -> row r=l15, h = nt*16 + lg*4 + j */  \
        _Pragma("unroll")                                                       \
        for (int mt = 0; mt < MT; ++mt)                                         \
            _Pragma("unroll")                                                   \
            for (int nt = 0; nt < 2; ++nt)                                      \
                acc1[mt][nt] = fzero;                                           \
        const char* cur = W1sB[hc % 3];                                         \
        _Pragma("unroll")                                                       \
        for (int kk = 0; kk < 8; ++kk) {                                        \
            half8 bfr[2];                                                       \
            _Pragma("unroll")                                                   \
            for (int nt = 0; nt < 2; ++nt) {                                    \
                int hr = nt * 16 + l15;                                         \
                bfr[nt] = *(const half8*)(cur + hr * 512 +                      \
                            ((kk * 64 + lg * 16) ^ ((hr & 7) << 4)));           \
            }                                                                   \
            _Pragma("unroll")                                                   \
            for (int mt = 0; mt < MT; ++mt)                                     \
                _Pragma("unroll")                                               \
                for (int nt = 0; nt < 2; ++nt)                                  \
                    acc1[mt][nt] = __builtin_amdgcn_mfma_f32_16x16x32_f16(      \
                        bfr[nt], afrag[mt][kk], acc1[mt][nt], 0, 0, 0);         \
        }                                                                       \
        /* bias + relu + cvt in regs -> GEMM2 B-frag (pre-permuted W2T) */      \
        {                                                                       \
            f32x4 bv0 = *(const f32x4*)(b1s + hc * HC + lg * 4);                \
            f32x4 bv1 = *(const f32x4*)(b1s + hc * HC + 16 + lg * 4);           \
            _Pragma("unroll")                                                   \
            for (int mt = 0; mt < MT; ++mt) {                                   \
                half8 hfrag;                                                    \
                _Pragma("unroll")                                               \
                for (int j = 0; j < 4; ++j) {                                   \
                    hfrag[j]     = (_Float16)fmaxf(acc1[mt][0][j] + bv0[j], 0.f);\
                    hfrag[4 + j] = (_Float16)fmaxf(acc1[mt][1][j] + bv1[j], 0.f);\
                }                                                               \
                _Pragma("unroll")                                               \
                for (int nt = 0; nt < 2; ++nt)                                  \
                    acc2[mt][nt] = __builtin_amdgcn_mfma_f32_16x16x32_f16(      \
                        W2USE[nt], hfrag, acc2[mt][nt], 0, 0, 0);               \
            }                                                                   \
        }                                                                       \
        /* counted barrier: drain DMA(hc+1) only; keep W2(2)+DMA(hc+2)(4). */   \
        if (hc < 14) {                                                          \
            asm volatile("s_waitcnt vmcnt(6)");                                 \
            __builtin_amdgcn_sched_barrier(0);                                  \
            __builtin_amdgcn_s_barrier();                                       \
        } else if (hc == 14) {                                                  \
            asm volatile("s_waitcnt vmcnt(2)");                                 \
            __builtin_amdgcn_sched_barrier(0);                                  \
            __builtin_amdgcn_s_barrier();                                       \
        } /* hc==15: last chunk, no barrier needed */                           \
    }

    #pragma unroll
    for (int h2 = 0; h2 < NCHUNK; h2 += 2) {
        CHUNK_BODY(h2, w2A, w2B);
        CHUNK_BODY(h2 + 1, w2B, w2A);
    }
#undef CHUNK_BODY

    // ---- scatter-store: out^T layout -> per-lane float4 stores ----
    const int m = min(BM, cnt - row_base);
    f32x4 b2v[2];
    #pragma unroll
    for (int nt = 0; nt < 2; ++nt)
        b2v[nt] = *(const f32x4*)(b2 + t * OUTD + nt * 16 + lg * 4);
    #pragma unroll
    for (int mt = 0; mt < MT; ++mt) {
        int rloc = wave * (MT * 16) + mt * 16 + l15;
        if (rloc < m) {
            int gr = idx_t[row_base + rloc];
            #pragma unroll
            for (int nt = 0; nt < 2; ++nt) {
                f32x4 v = acc2[mt][nt] + b2v[nt];
                __builtin_nontemporal_store(v, (f32x4*)(out + (size_t)gr * OUTD + nt * 16 + lg * 4));
            }
        }
    }
}

// ---------------- launch ----------------

extern "C" void kernel_launch(void* const* d_in, const int* in_sizes, int n_in,
                              void* d_out, int out_size, void* d_ws, size_t ws_size,
                              hipStream_t stream) {
    const float* x   = (const float*)d_in[0];
    const int* types = (const int*)d_in[1];
    const float* W1  = (const float*)d_in[2];
    const float* b1  = (const float*)d_in[3];
    const float* W2  = (const float*)d_in[4];
    const float* b2  = (const float*)d_in[5];
    float* out = (float*)d_out;

    char* ws = (char*)d_ws;
    int* meta = (int*)ws;                       // counts/offsets/tileoffs (13 ints)
    int* idx = (int*)(ws + 64);                 // N_TOK int32
    _Float16* W1T = (_Float16*)(ws + 64 + 4 * (size_t)N_TOK);
    _Float16* W2T = W1T + (size_t)NTYPE * HID * DM;
    // bc/bb alias the W1T region: used only BEFORE wprep_kernel writes W1T.
    int* bc = (int*)W1T;                        // [4][512]
    int* bb = bc + NTYPE * NBLK;                // [4][512]

    count_kernel<<<NBLK, 256, 0, stream>>>(types, bc);
    scan_blocks_kernel<<<1, 256, 0, stream>>>(bc, bb, meta);
    scatter2_kernel<<<NBLK, 256, 0, stream>>>(types, bb, idx);
    wprep_kernel<<<(NTYPE * HID * DM) / 256, 256, 0, stream>>>(W1, W2, W1T, W2T);

    fused_mlp_kernel<<<GX1D, 256, 0, stream>>>(x, meta, idx, W1T, W2T, b1, b2, out);
}

// Round 15
// 240.113 us; speedup vs baseline: 1.5589x; 1.1223x over previous
//
#include <hip/hip_runtime.h>
#include <hip/hip_bf16.h>
#include <hip/hip_fp16.h>

#define N_TOK 524288
#define DM 256
#define HID 512
#define OUTD 32
#define NTYPE 4
#define BM 128                     // rows per block (mt=2 per wave, 32 rows/wave)
#define MT 2
#define HC 32
#define NCHUNK (HID / HC)          // 16
#define CHUNK_BYTES (HC * DM * 2)  // 16384
#define NBLK 512                   // partition blocks; N_TOK = NBLK * 1024
#define GX1D (N_TOK / BM + NTYPE)  // exact tiles + per-type ceil slack

typedef _Float16 half8 __attribute__((ext_vector_type(8)));
typedef float f32x4 __attribute__((ext_vector_type(4)));

#define AS1 __attribute__((address_space(1)))
#define AS3 __attribute__((address_space(3)))

// ---------------- deterministic atomic-free partition ----------------

__global__ void count_kernel(const int* __restrict__ types, int* __restrict__ bc) {
    __shared__ int c[NTYPE];
    int tid = threadIdx.x;
    if (tid < NTYPE) c[tid] = 0;
    __syncthreads();
    int b = blockIdx.x;
    int lane = tid & 63;
    #pragma unroll
    for (int j = 0; j < 4; ++j) {
        int t = types[b * 1024 + j * 256 + tid];
        #pragma unroll
        for (int tt = 0; tt < NTYPE; ++tt) {
            unsigned long long mask = __ballot(t == tt);
            if (lane == 0) atomicAdd(&c[tt], __popcll(mask));
        }
    }
    __syncthreads();
    if (tid < NTYPE) bc[tid * NBLK + b] = c[tid];
}

// meta: [0..3] counts, [4..7] row offsets, [8..11] tile offsets, [12] total tiles
__global__ void scan_blocks_kernel(const int* __restrict__ bc,
                                   int* __restrict__ bb,
                                   int* __restrict__ meta) {
    __shared__ int totals[NTYPE];
    __shared__ int typeoff[NTYPE];
    int wave = threadIdx.x >> 6, lane = threadIdx.x & 63;
    int excl[NBLK / 64];
    int running = 0;
    #pragma unroll
    for (int it = 0; it < NBLK / 64; ++it) {
        int v = bc[wave * NBLK + it * 64 + lane];
        int s = v;
        #pragma unroll
        for (int d = 1; d < 64; d <<= 1) {
            int u = __shfl_up(s, d);
            if (lane >= d) s += u;
        }
        excl[it] = running + s - v;
        running += __shfl(s, 63);
    }
    if (lane == 0) totals[wave] = running;
    __syncthreads();
    if (threadIdx.x == 0) {
        int off = 0, toff = 0;
        for (int tt = 0; tt < NTYPE; ++tt) {
            typeoff[tt] = off;
            meta[tt] = totals[tt];
            meta[4 + tt] = off;
            meta[8 + tt] = toff;
            off += totals[tt];
            toff += (totals[tt] + BM - 1) / BM;
        }
        meta[12] = toff;
    }
    __syncthreads();
    #pragma unroll
    for (int it = 0; it < NBLK / 64; ++it)
        bb[wave * NBLK + it * 64 + lane] = typeoff[wave] + excl[it];
}

__global__ void scatter2_kernel(const int* __restrict__ types,
                                const int* __restrict__ bb,
                                int* __restrict__ idx) {
    __shared__ int base[NTYPE];
    __shared__ int wcnt[4][NTYPE];
    int b = blockIdx.x;
    int tid = threadIdx.x, wave = tid >> 6, lane = tid & 63;
    if (tid < NTYPE) base[tid] = bb[tid * NBLK + b];
    #pragma unroll
    for (int j = 0; j < 4; ++j) {
        __syncthreads();
        int i = b * 1024 + j * 256 + tid;
        int t = types[i];
        int rank = 0;
        #pragma unroll
        for (int tt = 0; tt < NTYPE; ++tt) {
            unsigned long long mask = __ballot(t == tt);
            if (t == tt) rank = __popcll(mask & ((1ull << lane) - 1ull));
            if (lane == 0) wcnt[wave][tt] = __popcll(mask);
        }
        __syncthreads();
        int pre = 0;
        for (int w = 0; w < wave; ++w) pre += wcnt[w][t];
        idx[base[t] + pre + rank] = i;
        __syncthreads();
        if (tid < NTYPE) {
            int tot = 0;
            #pragma unroll
            for (int w = 0; w < 4; ++w) tot += wcnt[w][tid];
            base[tid] += tot;
        }
    }
}

// ---------------- weight prep ----------------
// W1T: per type, 16 chunks of [32 h][256 d] f16, rows XOR-swizzled
// (byte_in_row = (d*2) ^ ((hr&7)<<4)), stored linearly in global_load_lds
// write order (inverse-swizzled source + swizzled read).
// W2T: [t][o][p] f16 with hidden dim PERMUTED per 32-chunk so the swapped-
// GEMM1 register output layout (h = nt*16 + lg*4 + j) is exactly the K=32
// B-operand slot order (p = lg*8 + j): p -> h1 = j<4 ? lg*4+j : 16+lg*4+(j-4)

__global__ void wprep_kernel(const float* __restrict__ W1, const float* __restrict__ W2,
                             _Float16* __restrict__ W1T, _Float16* __restrict__ W2T) {
    int i = blockIdx.x * blockDim.x + threadIdx.x;
    if (i < NTYPE * HID * DM) {
        int t = i / (HID * DM);
        int r = i - t * (HID * DM);
        int byteoff = r * 2;
        int hc = byteoff / CHUNK_BYTES;
        int rem = byteoff - hc * CHUNK_BYTES;
        int hr = rem >> 9;
        int brow = rem & 511;
        int d = (brow ^ ((hr & 7) << 4)) >> 1;
        int h = hc * HC + hr;
        W1T[i] = (_Float16)W1[(t * DM + d) * HID + h];
    }
    if (i < NTYPE * OUTD * HID) {
        int t = i / (OUTD * HID);
        int r = i - t * (OUTD * HID);
        int o = r / HID;
        int pg = r - o * HID;          // permuted k position
        int hc = pg >> 5;
        int p = pg & 31;
        int lg = p >> 3, j = p & 7;
        int h1 = (j < 4) ? (lg * 4 + j) : (16 + lg * 4 + (j - 4));
        int h = hc * HC + h1;
        W2T[i] = (_Float16)W2[(t * HID + h) * OUTD + o];
    }
}

// ---------------- fused grouped MLP (depth-4 gather + reg-H) ----------
// 256 threads = 4 waves; block = 128 gathered rows of one type (32/wave).
// GATHER: 2-row groups, FOUR groups (8 row-DMAs, 8 KB) in flight per wave
// (R11 was 4-row groups depth 2 -> per-group stall ~= full HBM latency;
// depth 4 cuts the exposed latency per step to ~L/4). Row r's 1 KB is read
// contiguously by 64 lanes with per-lane source rotated by ((lane-r)&63)*16;
// redistribute un-rotates via (B + r*16) & 1023. The 8 active redist lanes
// (2 rows x 4 lg) hit disjoint 16B slots mod 128 (rows differ by 16 in
// rotation) -> bank-conflict-free.
// CHUNK LOOP: identical to R11 (W1 dbuf DMA 1 ahead, W2 reg ping-pong,
// reg-H via swapped MFMA + permuted W2T, plain __syncthreads).

__launch_bounds__(256)
__global__ void fused_mlp_kernel(const float* __restrict__ x,
                                 const int* __restrict__ meta,
                                 const int* __restrict__ idx,
                                 const _Float16* __restrict__ W1T,
                                 const _Float16* __restrict__ W2T,
                                 const float* __restrict__ b1,
                                 const float* __restrict__ b2,
                                 float* __restrict__ out) {
    const int b = blockIdx.x;
    if (b >= meta[12]) return;
    const int t = (b >= meta[9]) + (b >= meta[10]) + (b >= meta[11]);
    const int cnt = meta[t];
    const int row_base = (b - meta[8 + t]) * BM;
    const int* idx_t = idx + meta[4 + t];

    __shared__ __align__(16) char W1sB[2][CHUNK_BYTES];  // 32 KB dbuf (+ gather scratch)
    __shared__ __align__(16) float b1s[HID];             // 2 KB

    const int tid = threadIdx.x;
    const int wave = tid >> 6;
    const int lane = tid & 63;
    const int l15 = lane & 15;
    const int lg = lane >> 4;

    // bias -> LDS (before any gather DMA; its compiler vmcnt wait lands here)
    {
        float2 bv = *(const float2*)(b1 + t * HID + tid * 2);
        b1s[tid * 2] = bv.x;
        b1s[tid * 2 + 1] = bv.y;
    }
    __builtin_amdgcn_sched_barrier(0);

    // preload this wave's 32 row ids (keeps the gather vmcnt count exact)
    int rg[32];
    #pragma unroll
    for (int r = 0; r < 32; ++r)
        rg[r] = idx_t[min(row_base + wave * 32 + r, cnt - 1)];
    __builtin_amdgcn_sched_barrier(0);

    // ---- gather: 32 rows/wave, 16 groups of 2 rows, 4 groups in flight ----
    half8 afrag[MT][8];
    char* scratch = &W1sB[0][0] + wave * 8192;   // 4 x 2 KB slots

#define G2_ISSUE(G)                                                            \
    {                                                                          \
        _Pragma("unroll")                                                      \
        for (int i = 0; i < 2; ++i) {                                          \
            int r = 2 * (G) + i;                                               \
            const char* src = (const char*)(x + (size_t)rg[r] * DM)            \
                              + ((lane - r) & 63) * 16;                        \
            __builtin_amdgcn_global_load_lds(                                  \
                (const AS1 void*)src,                                          \
                (AS3 void*)(scratch + ((G) & 3) * 2048 + i * 1024 + lane * 16),\
                16, 0, 0);                                                     \
        }                                                                      \
    }

#define G2_REDIST(G)                                                           \
    if ((l15 >> 1) == ((G) & 7)) {                                             \
        const int p = l15 & 1;                                                 \
        const int r = 2 * (G) + p;                                             \
        const char* gb = scratch + ((G) & 3) * 2048 + p * 1024;                \
        _Pragma("unroll")                                                      \
        for (int kk = 0; kk < 8; ++kk) {                                       \
            int B0 = kk * 128 + lg * 32 + r * 16;                              \
            f32x4 v0 = *(const f32x4*)(gb + (B0 & 1023));                      \
            f32x4 v1 = *(const f32x4*)(gb + ((B0 + 16) & 1023));               \
            half8 h;                                                           \
            h[0] = (_Float16)v0[0]; h[1] = (_Float16)v0[1];                    \
            h[2] = (_Float16)v0[2]; h[3] = (_Float16)v0[3];                    \
            h[4] = (_Float16)v1[0]; h[5] = (_Float16)v1[1];                    \
            h[6] = (_Float16)v1[2]; h[7] = (_Float16)v1[3];                    \
            afrag[(G) >> 3][kk] = h;                                           \
        }                                                                      \
    }

#define G2_STEP(G, VN)                                                         \
    __builtin_amdgcn_sched_barrier(0);                                         \
    if ((G) + 3 < 16) { G2_ISSUE((G) + 3) }                                    \
    __builtin_amdgcn_sched_barrier(0);                                         \
    asm volatile("s_waitcnt vmcnt(" #VN ")");                                  \
    __builtin_amdgcn_sched_barrier(0);                                         \
    G2_REDIST(G)

    G2_ISSUE(0) G2_ISSUE(1) G2_ISSUE(2)
    G2_STEP(0, 6)  G2_STEP(1, 6)  G2_STEP(2, 6)  G2_STEP(3, 6)
    G2_STEP(4, 6)  G2_STEP(5, 6)  G2_STEP(6, 6)  G2_STEP(7, 6)
    G2_STEP(8, 6)  G2_STEP(9, 6)  G2_STEP(10, 6) G2_STEP(11, 6)
    G2_STEP(12, 6) G2_STEP(13, 4) G2_STEP(14, 2) G2_STEP(15, 0)
#undef G2_STEP
#undef G2_REDIST
#undef G2_ISSUE

    __syncthreads();  // all waves done with W1sB-as-scratch

    const f32x4 fzero = {0.f, 0.f, 0.f, 0.f};
    f32x4 acc2[MT][2];   // out^T frags: lane holds o = nt2*16 + lg*4 + j for row l15
    #pragma unroll
    for (int mt = 0; mt < MT; ++mt)
        #pragma unroll
        for (int nt = 0; nt < 2; ++nt)
            acc2[mt][nt] = fzero;

    const char* w1base = (const char*)(W1T + (size_t)t * HID * DM);
    const _Float16* w2t_t = W2T + (size_t)t * OUTD * HID;

    // stage chunk 0 + W2 frags chunk 0
    #pragma unroll
    for (int it = 0; it < 4; ++it) {
        __builtin_amdgcn_global_load_lds(
            (const AS1 void*)(w1base + it * 4096 + tid * 16),
            (AS3 void*)(&W1sB[0][it * 4096 + tid * 16]),
            16, 0, 0);
    }
    half8 w2A[2], w2B[2];
    #pragma unroll
    for (int nt = 0; nt < 2; ++nt)
        w2A[nt] = *(const half8*)(w2t_t + (nt * 16 + l15) * HID + lg * 8);
    __syncthreads();  // chunk0 DMA drained (vmcnt0 at barrier)

#define CHUNK_BODY(HCI, W2USE, W2FILL)                                          \
    {                                                                           \
        const int hc = (HCI);                                                   \
        const char* cur = W1sB[hc & 1];                                         \
        if (hc + 1 < NCHUNK) {                                                  \
            const char* src = w1base + (size_t)(hc + 1) * CHUNK_BYTES;          \
            char* dst = W1sB[(hc + 1) & 1];                                     \
            _Pragma("unroll")                                                   \
            for (int it = 0; it < 4; ++it) {                                    \
                __builtin_amdgcn_global_load_lds(                               \
                    (const AS1 void*)(src + it * 4096 + tid * 16),              \
                    (AS3 void*)(dst + it * 4096 + tid * 16),                    \
                    16, 0, 0);                                                  \
            }                                                                   \
        }                                                                       \
        {   /* prefetch W2 frags for chunk hc+1 (wrap harmless) */              \
            int hn = (hc + 1) & 15;                                             \
            _Pragma("unroll")                                                   \
            for (int nt = 0; nt < 2; ++nt)                                      \
                W2FILL[nt] = *(const half8*)(w2t_t + (nt * 16 + l15) * HID + hn * HC + lg * 8); \
        }                                                                       \
        f32x4 acc1[MT][2];  /* H^T: lane -> row r=l15, h = nt*16 + lg*4 + j */  \
        _Pragma("unroll")                                                       \
        for (int mt = 0; mt < MT; ++mt)                                         \
            _Pragma("unroll")                                                   \
            for (int nt = 0; nt < 2; ++nt)                                      \
                acc1[mt][nt] = fzero;                                           \
        _Pragma("unroll")                                                       \
        for (int kk = 0; kk < 8; ++kk) {                                        \
            half8 bfr[2];                                                       \
            _Pragma("unroll")                                                   \
            for (int nt = 0; nt < 2; ++nt) {                                    \
                int hr = nt * 16 + l15;                                         \
                bfr[nt] = *(const half8*)(cur + hr * 512 +                      \
                            ((kk * 64 + lg * 16) ^ ((hr & 7) << 4)));           \
            }                                                                   \
            _Pragma("unroll")                                                   \
            for (int mt = 0; mt < MT; ++mt)                                     \
                _Pragma("unroll")                                               \
                for (int nt = 0; nt < 2; ++nt)                                  \
                    acc1[mt][nt] = __builtin_amdgcn_mfma_f32_16x16x32_f16(      \
                        bfr[nt], afrag[mt][kk], acc1[mt][nt], 0, 0, 0);         \
        }                                                                       \
        /* bias + relu + cvt in regs -> GEMM2 B-frag (pre-permuted W2T) */      \
        {                                                                       \
            f32x4 bv0 = *(const f32x4*)(b1s + hc * HC + lg * 4);                \
            f32x4 bv1 = *(const f32x4*)(b1s + hc * HC + 16 + lg * 4);           \
            _Pragma("unroll")                                                   \
            for (int mt = 0; mt < MT; ++mt) {                                   \
                half8 hfrag;                                                    \
                _Pragma("unroll")                                               \
                for (int j = 0; j < 4; ++j) {                                   \
                    hfrag[j]     = (_Float16)fmaxf(acc1[mt][0][j] + bv0[j], 0.f);\
                    hfrag[4 + j] = (_Float16)fmaxf(acc1[mt][1][j] + bv1[j], 0.f);\
                }                                                               \
                _Pragma("unroll")                                               \
                for (int nt = 0; nt < 2; ++nt)                                  \
                    acc2[mt][nt] = __builtin_amdgcn_mfma_f32_16x16x32_f16(      \
                        W2USE[nt], hfrag, acc2[mt][nt], 0, 0, 0);               \
            }                                                                   \
        }                                                                       \
        __syncthreads(); /* drains next-chunk DMA; issued one chunk earlier */  \
    }

    #pragma unroll
    for (int h2 = 0; h2 < NCHUNK; h2 += 2) {
        CHUNK_BODY(h2, w2A, w2B);
        CHUNK_BODY(h2 + 1, w2B, w2A);
    }
#undef CHUNK_BODY

    // ---- scatter-store: out^T layout -> per-lane float4 stores ----
    const int m = min(BM, cnt - row_base);
    f32x4 b2v[2];
    #pragma unroll
    for (int nt = 0; nt < 2; ++nt)
        b2v[nt] = *(const f32x4*)(b2 + t * OUTD + nt * 16 + lg * 4);
    #pragma unroll
    for (int mt = 0; mt < MT; ++mt) {
        int rloc = wave * (MT * 16) + mt * 16 + l15;
        if (rloc < m) {
            int gr = idx_t[row_base + rloc];
            #pragma unroll
            for (int nt = 0; nt < 2; ++nt) {
                f32x4 v = acc2[mt][nt] + b2v[nt];
                __builtin_nontemporal_store(v, (f32x4*)(out + (size_t)gr * OUTD + nt * 16 + lg * 4));
            }
        }
    }
}

// ---------------- launch ----------------

extern "C" void kernel_launch(void* const* d_in, const int* in_sizes, int n_in,
                              void* d_out, int out_size, void* d_ws, size_t ws_size,
                              hipStream_t stream) {
    const float* x   = (const float*)d_in[0];
    const int* types = (const int*)d_in[1];
    const float* W1  = (const float*)d_in[2];
    const float* b1  = (const float*)d_in[3];
    const float* W2  = (const float*)d_in[4];
    const float* b2  = (const float*)d_in[5];
    float* out = (float*)d_out;

    char* ws = (char*)d_ws;
    int* meta = (int*)ws;                       // counts/offsets/tileoffs (13 ints)
    int* idx = (int*)(ws + 64);                 // N_TOK int32
    _Float16* W1T = (_Float16*)(ws + 64 + 4 * (size_t)N_TOK);
    _Float16* W2T = W1T + (size_t)NTYPE * HID * DM;
    // bc/bb alias the W1T region: used only BEFORE wprep_kernel writes W1T.
    int* bc = (int*)W1T;                        // [4][512]
    int* bb = bc + NTYPE * NBLK;                // [4][512]

    count_kernel<<<NBLK, 256, 0, stream>>>(types, bc);
    scan_blocks_kernel<<<1, 256, 0, stream>>>(bc, bb, meta);
    scatter2_kernel<<<NBLK, 256, 0, stream>>>(types, bb, idx);
    wprep_kernel<<<(NTYPE * HID * DM) / 256, 256, 0, stream>>>(W1, W2, W1T, W2T);

    fused_mlp_kernel<<<GX1D, 256, 0, stream>>>(x, meta, idx, W1T, W2T, b1, b2, out);
}